// Round 1
// baseline (174.549 us; speedup 1.0000x reference)
//
#include <hip/hip_runtime.h>

#define S_LEN  4096
#define DM     6
#define NLAYER 4
#define NFF    64
#define HALO   8
#define TPB    256
#define TILE_OUT (TPB - 2*HALO)   // 240 output positions per block

// LayerNorm over 6 elements held in registers.
__device__ __forceinline__ void ln6(float* v, const float* __restrict__ w,
                                    const float* __restrict__ b) {
    float mu = (((v[0]+v[1])+(v[2]+v[3]))+(v[4]+v[5])) * (1.0f/6.0f);
    float var = 0.0f;
#pragma unroll
    for (int d = 0; d < DM; ++d) { float dd = v[d]-mu; var = fmaf(dd, dd, var); }
    float r = rsqrtf(fmaf(var, 1.0f/6.0f, 1e-6f));
#pragma unroll
    for (int d = 0; d < DM; ++d) v[d] = fmaf((v[d]-mu)*r, w[d], b[d]);
}

__global__ __launch_bounds__(TPB)
void decoder_fused(const float* __restrict__ x_batch,
                   const float* __restrict__ dec_ln_w, const float* __restrict__ dec_ln_b,
                   const float* __restrict__ qw, const float* __restrict__ qb,
                   const float* __restrict__ kw, const float* __restrict__ kb,
                   const float* __restrict__ vw, const float* __restrict__ vb,
                   const float* __restrict__ mha_ln_w, const float* __restrict__ mha_ln_b,
                   const float* __restrict__ ffn_w1, const float* __restrict__ ffn_b1,
                   const float* __restrict__ ffn_w2, const float* __restrict__ ffn_b2,
                   const float* __restrict__ ffn_ln_w, const float* __restrict__ ffn_ln_b,
                   float* __restrict__ out) {
    const int t = threadIdx.x;
    const int b = blockIdx.y;
    const int p  = blockIdx.x * TILE_OUT + t - HALO;          // global seq position
    const int pc = min(max(p, 0), S_LEN - 1);                  // clamped for load

    // SoA exchange buffer: xs[d][t]; stride-1 across lanes -> conflict-free.
    __shared__ float xs[DM][TPB];

    float x[DM];
    {
        const float2* src = reinterpret_cast<const float2*>(
            x_batch + ((size_t)b * S_LEN + pc) * DM);          // 8B-aligned (24B stride)
        float2 a0 = src[0], a1 = src[1], a2 = src[2];
        x[0]=a0.x; x[1]=a0.y; x[2]=a1.x; x[3]=a1.y; x[4]=a2.x; x[5]=a2.y;
    }

    ln6(x, dec_ln_w, dec_ln_b);

#pragma unroll 1
    for (int li = 0; li < NLAYER; ++li) {
        // -------- two mha blocks (ai = 0, 1) --------
#pragma unroll 1
        for (int ai = 0; ai < 2; ++ai) {
            const int base = (li*2 + ai) * DM;

            // neighbor exchange (roll +-1 along seq)
#pragma unroll
            for (int d = 0; d < DM; ++d) xs[d][t] = x[d];
            __syncthreads();
            const int tm = (t == 0)       ? 0       : t - 1;
            const int tp = (t == TPB - 1) ? TPB - 1 : t + 1;
            float xm[DM], xpl[DM];
#pragma unroll
            for (int d = 0; d < DM; ++d) { xm[d] = xs[d][tm]; xpl[d] = xs[d][tp]; }
            __syncthreads();
            if (p <= 0) {                       // global first row: k_in = x itself
#pragma unroll
                for (int d = 0; d < DM; ++d) xm[d] = x[d];
            }
            if (p >= S_LEN - 1) {               // global last row: v_in = x itself
#pragma unroll
                for (int d = 0; d < DM; ++d) xpl[d] = x[d];
            }

            // autocorr: softmax over constant == 1/S  =>  out = teo/S
#pragma unroll
            for (int d = 0; d < DM; ++d) {
                float q = fmaf(x[d],   qw[base+d], qb[base+d]);
                float k = fmaf(xm[d],  kw[base+d], kb[base+d]);
                float v = fmaf(xpl[d], vw[base+d], vb[base+d]);
                float teo = fmaf(q, q, -(k*v));
                x[d] = fmaf(teo, 1.0f/(float)S_LEN, x[d]);     // out + residual x
            }
            ln6(x, mha_ln_w + base, mha_ln_b + base);
        }

        // -------- FFN: y = W2 * relu(W1 x + b1) + b2 + x --------
        {
            const float* w1 = ffn_w1 + li*NFF*DM;
            const float* w2 = ffn_w2 + li*DM*NFF;
            const float* b1 = ffn_b1 + li*NFF;
            const float* b2 = ffn_b2 + li*DM;
            float y[DM];
#pragma unroll
            for (int d = 0; d < DM; ++d) y[d] = x[d] + b2[d];
#pragma unroll 8
            for (int f = 0; f < NFF; ++f) {
                float hf = b1[f];
#pragma unroll
                for (int d = 0; d < DM; ++d) hf = fmaf(x[d], w1[f*DM + d], hf);
                hf = fmaxf(hf, 0.0f);
#pragma unroll
                for (int d = 0; d < DM; ++d) y[d] = fmaf(hf, w2[d*NFF + f], y[d]);
            }
#pragma unroll
            for (int d = 0; d < DM; ++d) x[d] = y[d];
            ln6(x, ffn_ln_w + li*DM, ffn_ln_b + li*DM);
        }
    }

    // write only the valid (non-halo) positions
    if (t >= HALO && t < TPB - HALO && p < S_LEN) {
        float2* dst = reinterpret_cast<float2*>(out + ((size_t)b * S_LEN + p) * DM);
        dst[0] = make_float2(x[0], x[1]);
        dst[1] = make_float2(x[2], x[3]);
        dst[2] = make_float2(x[4], x[5]);
    }
}

extern "C" void kernel_launch(void* const* d_in, const int* in_sizes, int n_in,
                              void* d_out, int out_size, void* d_ws, size_t ws_size,
                              hipStream_t stream) {
    const float* x_batch  = (const float*)d_in[0];
    // d_in[1] enc_output: unused by the reference
    const float* dec_ln_w = (const float*)d_in[2];
    const float* dec_ln_b = (const float*)d_in[3];
    const float* qw       = (const float*)d_in[4];
    const float* qb       = (const float*)d_in[5];
    const float* kw       = (const float*)d_in[6];
    const float* kb       = (const float*)d_in[7];
    const float* vw       = (const float*)d_in[8];
    const float* vb       = (const float*)d_in[9];
    // d_in[10], d_in[11] ln1_w/ln1_b: dead (softmax of a constant)
    const float* mha_ln_w = (const float*)d_in[12];
    const float* mha_ln_b = (const float*)d_in[13];
    const float* ffn_w1   = (const float*)d_in[14];
    const float* ffn_b1   = (const float*)d_in[15];
    const float* ffn_w2   = (const float*)d_in[16];
    const float* ffn_b2   = (const float*)d_in[17];
    const float* ffn_ln_w = (const float*)d_in[18];
    const float* ffn_ln_b = (const float*)d_in[19];
    float* out = (float*)d_out;

    const int B = in_sizes[0] / (S_LEN * DM);   // 128
    dim3 grid((S_LEN + TILE_OUT - 1) / TILE_OUT, B);
    decoder_fused<<<grid, TPB, 0, stream>>>(
        x_batch, dec_ln_w, dec_ln_b, qw, qb, kw, kb, vw, vb,
        mha_ln_w, mha_ln_b, ffn_w1, ffn_b1, ffn_w2, ffn_b2,
        ffn_ln_w, ffn_ln_b, out);
}

// Round 2
// 160.244 us; speedup vs baseline: 1.0893x; 1.0893x over previous
//
#include <hip/hip_runtime.h>

#define S_LEN  4096
#define DM     6
#define NLAYER 4
#define NFF    64
#define HALO   8
#define TPB    256
#define TILE_OUT (TPB - 2*HALO)   // 240 output positions per block

typedef float    vf2 __attribute__((ext_vector_type(2)));
typedef _Float16 vh2 __attribute__((ext_vector_type(2)));

// packed-weight workspace layout (uint32 entries, each = f16 weight duplicated
// into both halves so v_pk_fma_f16 can take it straight from one SGPR)
#define B1P_OFF (NLAYER*NFF*DM)              // after w1: 1536
#define W2P_OFF (B1P_OFF + NLAYER*NFF)       // after b1: 1792
#define PACK_TOTAL (W2P_OFF + NLAYER*NFF*DM) // 3328 u32 = 13.3 KB

__device__ __forceinline__ vf2 splat2(float s){ vf2 r; r.x = s; r.y = s; return r; }
__device__ __forceinline__ vh2 bch2(unsigned u){ return __builtin_bit_cast(vh2, u); }

__global__ void prep_weights(const float* __restrict__ w1,
                             const float* __restrict__ b1,
                             const float* __restrict__ w2,
                             unsigned* __restrict__ ws) {
    int i = blockIdx.x * 256 + threadIdx.x;
    if (i >= PACK_TOTAL) return;
    float v;
    if (i < B1P_OFF) {
        v = w1[i];                                   // [L][64][6], already contiguous
    } else if (i < W2P_OFF) {
        v = b1[i - B1P_OFF];                         // [L][64]
    } else {
        int r  = i - W2P_OFF;                        // transpose w2 [L][6][64] -> [L][64][6]
        int li = r / (NFF*DM);
        int q  = r % (NFF*DM);
        int f  = q / DM, d = q % DM;
        v = w2[li*(DM*NFF) + d*NFF + f];
    }
    _Float16 h = (_Float16)v;
    unsigned short bits = __builtin_bit_cast(unsigned short, h);
    ws[i] = (unsigned)bits | ((unsigned)bits << 16);
}

// LayerNorm over 6 elements, two samples packed per vf2 lane-pair.
__device__ __forceinline__ void ln6v(vf2* v, const float* __restrict__ w,
                                     const float* __restrict__ b) {
    vf2 mu = (((v[0]+v[1])+(v[2]+v[3]))+(v[4]+v[5])) * (1.0f/6.0f);
    vf2 var = splat2(0.0f);
#pragma unroll
    for (int d = 0; d < DM; ++d) { vf2 dd = v[d]-mu; var = __builtin_elementwise_fma(dd, dd, var); }
    vf2 a = var * (1.0f/6.0f) + splat2(1e-6f);
    vf2 r; r.x = rsqrtf(a.x); r.y = rsqrtf(a.y);
#pragma unroll
    for (int d = 0; d < DM; ++d)
        v[d] = __builtin_elementwise_fma((v[d]-mu)*r, splat2(w[d]), splat2(b[d]));
}

__global__ __launch_bounds__(TPB)
void decoder_fused(const float* __restrict__ x_batch,
                   const float* __restrict__ dec_ln_w, const float* __restrict__ dec_ln_b,
                   const float* __restrict__ qw, const float* __restrict__ qb,
                   const float* __restrict__ kw, const float* __restrict__ kb,
                   const float* __restrict__ vw, const float* __restrict__ vb,
                   const float* __restrict__ mha_ln_w, const float* __restrict__ mha_ln_b,
                   const unsigned* __restrict__ wsp,                       // packed f16 weights
                   const float* __restrict__ ffn_b2,
                   const float* __restrict__ ffn_ln_w, const float* __restrict__ ffn_ln_b,
                   float* __restrict__ out) {
    const int t  = threadIdx.x;
    const int bp = blockIdx.y;                 // batch PAIR index
    const int b0 = 2*bp, b1 = 2*bp + 1;
    const int p  = blockIdx.x * TILE_OUT + t - HALO;
    const int pc = min(max(p, 0), S_LEN - 1);

    // double-buffered SoA exchange: one barrier per mha stage
    __shared__ vf2 xs[2][DM][TPB];

    vf2 x2[DM];
    {
        const float2* sA = reinterpret_cast<const float2*>(x_batch + ((size_t)b0 * S_LEN + pc) * DM);
        const float2* sB = reinterpret_cast<const float2*>(x_batch + ((size_t)b1 * S_LEN + pc) * DM);
        float2 a0 = sA[0], a1 = sA[1], a2 = sA[2];
        float2 c0 = sB[0], c1 = sB[1], c2 = sB[2];
        x2[0].x=a0.x; x2[1].x=a0.y; x2[2].x=a1.x; x2[3].x=a1.y; x2[4].x=a2.x; x2[5].x=a2.y;
        x2[0].y=c0.x; x2[1].y=c0.y; x2[2].y=c1.x; x2[3].y=c1.y; x2[4].y=c2.x; x2[5].y=c2.y;
    }

    ln6v(x2, dec_ln_w, dec_ln_b);

#pragma unroll 1
    for (int li = 0; li < NLAYER; ++li) {
        // -------- two mha blocks --------
#pragma unroll 1
        for (int ai = 0; ai < 2; ++ai) {
            const int st   = li*2 + ai;
            const int buf  = st & 1;
            const int base = st * DM;

#pragma unroll
            for (int d = 0; d < DM; ++d) xs[buf][d][t] = x2[d];
            __syncthreads();
            const int tm = (t == 0)       ? 0       : t - 1;
            const int tp = (t == TPB - 1) ? TPB - 1 : t + 1;
            vf2 xm[DM], xpl[DM];
#pragma unroll
            for (int d = 0; d < DM; ++d) { xm[d] = xs[buf][d][tm]; xpl[d] = xs[buf][d][tp]; }
            if (p <= 0) {
#pragma unroll
                for (int d = 0; d < DM; ++d) xm[d] = x2[d];
            }
            if (p >= S_LEN - 1) {
#pragma unroll
                for (int d = 0; d < DM; ++d) xpl[d] = x2[d];
            }

            // softmax over a seq-constant == 1/S  =>  out = teo/S (+ residual)
#pragma unroll
            for (int d = 0; d < DM; ++d) {
                vf2 q = __builtin_elementwise_fma(x2[d],  splat2(qw[base+d]), splat2(qb[base+d]));
                vf2 k = __builtin_elementwise_fma(xm[d],  splat2(kw[base+d]), splat2(kb[base+d]));
                vf2 v = __builtin_elementwise_fma(xpl[d], splat2(vw[base+d]), splat2(vb[base+d]));
                vf2 teo = __builtin_elementwise_fma(q, q, -(k*v));
                x2[d] = __builtin_elementwise_fma(teo, splat2(1.0f/(float)S_LEN), x2[d]);
            }
            ln6v(x2, mha_ln_w + base, mha_ln_b + base);
        }

        // -------- FFN in packed f16 (v_pk_fma_f16), two samples per lane --------
        {
            const unsigned* w1p = wsp + (size_t)li*NFF*DM;
            const unsigned* b1p = wsp + B1P_OFF + (size_t)li*NFF;
            const unsigned* w2p = wsp + W2P_OFF + (size_t)li*NFF*DM;
            const float*    b2  = ffn_b2 + li*DM;

            vh2 xh[DM];
#pragma unroll
            for (int d = 0; d < DM; ++d) { xh[d].x = (_Float16)x2[d].x; xh[d].y = (_Float16)x2[d].y; }
            vh2 ya[DM], yb[DM];
#pragma unroll
            for (int d = 0; d < DM; ++d) { ya[d] = (vh2)(_Float16)0; yb[d] = (vh2)(_Float16)0; }

#pragma unroll 4
            for (int f = 0; f < NFF; f += 2) {
                vh2 h0 = bch2(b1p[f]);
                vh2 h1 = bch2(b1p[f+1]);
#pragma unroll
                for (int d = 0; d < DM; ++d) {
                    h0 = __builtin_elementwise_fma(xh[d], bch2(w1p[f*DM + d]),     h0);
                    h1 = __builtin_elementwise_fma(xh[d], bch2(w1p[(f+1)*DM + d]), h1);
                }
                vh2 z = (vh2)(_Float16)0;
                h0 = __builtin_elementwise_max(h0, z);
                h1 = __builtin_elementwise_max(h1, z);
#pragma unroll
                for (int d = 0; d < DM; ++d) {
                    ya[d] = __builtin_elementwise_fma(h0, bch2(w2p[f*DM + d]),     ya[d]);
                    yb[d] = __builtin_elementwise_fma(h1, bch2(w2p[(f+1)*DM + d]), yb[d]);
                }
            }
#pragma unroll
            for (int d = 0; d < DM; ++d) {
                x2[d].x = x2[d].x + b2[d] + ((float)ya[d].x + (float)yb[d].x);
                x2[d].y = x2[d].y + b2[d] + ((float)ya[d].y + (float)yb[d].y);
            }
            ln6v(x2, ffn_ln_w + li*DM, ffn_ln_b + li*DM);
        }
    }

    if (t >= HALO && t < TPB - HALO && p < S_LEN) {
        float2* dA = reinterpret_cast<float2*>(out + ((size_t)b0 * S_LEN + p) * DM);
        float2* dB = reinterpret_cast<float2*>(out + ((size_t)b1 * S_LEN + p) * DM);
        dA[0] = make_float2(x2[0].x, x2[1].x);
        dA[1] = make_float2(x2[2].x, x2[3].x);
        dA[2] = make_float2(x2[4].x, x2[5].x);
        dB[0] = make_float2(x2[0].y, x2[1].y);
        dB[1] = make_float2(x2[2].y, x2[3].y);
        dB[2] = make_float2(x2[4].y, x2[5].y);
    }
}

extern "C" void kernel_launch(void* const* d_in, const int* in_sizes, int n_in,
                              void* d_out, int out_size, void* d_ws, size_t ws_size,
                              hipStream_t stream) {
    const float* x_batch  = (const float*)d_in[0];
    // d_in[1] enc_output: unused by the reference
    const float* dec_ln_w = (const float*)d_in[2];
    const float* dec_ln_b = (const float*)d_in[3];
    const float* qw       = (const float*)d_in[4];
    const float* qb       = (const float*)d_in[5];
    const float* kw       = (const float*)d_in[6];
    const float* kb       = (const float*)d_in[7];
    const float* vw       = (const float*)d_in[8];
    const float* vb       = (const float*)d_in[9];
    // d_in[10..11] ln1_w/ln1_b: dead (softmax of a seq-constant)
    const float* mha_ln_w = (const float*)d_in[12];
    const float* mha_ln_b = (const float*)d_in[13];
    const float* ffn_w1   = (const float*)d_in[14];
    const float* ffn_b1   = (const float*)d_in[15];
    const float* ffn_w2   = (const float*)d_in[16];
    const float* ffn_b2   = (const float*)d_in[17];
    const float* ffn_ln_w = (const float*)d_in[18];
    const float* ffn_ln_b = (const float*)d_in[19];
    float* out = (float*)d_out;
    unsigned* wsp = (unsigned*)d_ws;

    prep_weights<<<(PACK_TOTAL + 255)/256, 256, 0, stream>>>(ffn_w1, ffn_b1, ffn_w2, wsp);

    const int B  = in_sizes[0] / (S_LEN * DM);   // 128
    const int BP = B / 2;                        // batch pairs
    dim3 grid((S_LEN + TILE_OUT - 1) / TILE_OUT, BP);
    decoder_fused<<<grid, TPB, 0, stream>>>(
        x_batch, dec_ln_w, dec_ln_b, qw, qb, kw, kb, vw, vb,
        mha_ln_w, mha_ln_b, wsp, ffn_b2, ffn_ln_w, ffn_ln_b, out);
}

// Round 3
// 159.903 us; speedup vs baseline: 1.0916x; 1.0021x over previous
//
#include <hip/hip_runtime.h>

#define S_LEN  4096
#define DM     6
#define NLAYER 4
#define NFF    64
#define HALO   8
#define TPB    256
#define OUT_PER_WAVE 112              // wave holds 128 positions, outputs 112
#define WAVES_PER_BATCH 37            // ceil(4096/112)
#define BLK_X 10                      // ceil(37 / 4 waves-per-block)

typedef float    vf2 __attribute__((ext_vector_type(2)));
typedef _Float16 vh2 __attribute__((ext_vector_type(2)));

// packed-weight workspace layout (uint32 entries, each = f16 weight duplicated
// into both halves so v_pk_fma_f16 takes it straight from one SGPR)
#define B1P_OFF (NLAYER*NFF*DM)              // after w1: 1536
#define W2P_OFF (B1P_OFF + NLAYER*NFF)       // after b1: 1792
#define PACK_TOTAL (W2P_OFF + NLAYER*NFF*DM) // 3328 u32

__device__ __forceinline__ vf2 splat2(float s){ vf2 r; r.x = s; r.y = s; return r; }
__device__ __forceinline__ vh2 bch2(unsigned u){ return __builtin_bit_cast(vh2, u); }

__global__ void prep_weights(const float* __restrict__ w1,
                             const float* __restrict__ b1,
                             const float* __restrict__ w2,
                             unsigned* __restrict__ ws) {
    int i = blockIdx.x * 256 + threadIdx.x;
    if (i >= PACK_TOTAL) return;
    float v;
    if (i < B1P_OFF) {
        v = w1[i];                                   // [L][64][6] contiguous
    } else if (i < W2P_OFF) {
        v = b1[i - B1P_OFF];                         // [L][64]
    } else {
        int r  = i - W2P_OFF;                        // transpose w2 [L][6][64] -> [L][64][6]
        int li = r / (NFF*DM);
        int q  = r % (NFF*DM);
        int f  = q / DM, d = q % DM;
        v = w2[li*(DM*NFF) + d*NFF + f];
    }
    _Float16 h = (_Float16)v;
    unsigned short bits = __builtin_bit_cast(unsigned short, h);
    ws[i] = (unsigned)bits | ((unsigned)bits << 16);
}

// LayerNorm over 6 dims, two seq positions packed per vf2.
__device__ __forceinline__ void ln6v(vf2* v, const float* __restrict__ w,
                                     const float* __restrict__ b) {
    vf2 mu = (((v[0]+v[1])+(v[2]+v[3]))+(v[4]+v[5])) * (1.0f/6.0f);
    vf2 var = splat2(0.0f);
#pragma unroll
    for (int d = 0; d < DM; ++d) { vf2 dd = v[d]-mu; var = __builtin_elementwise_fma(dd, dd, var); }
    vf2 a = var * (1.0f/6.0f) + splat2(1e-6f);
    vf2 r; r.x = rsqrtf(a.x); r.y = rsqrtf(a.y);
#pragma unroll
    for (int d = 0; d < DM; ++d)
        v[d] = __builtin_elementwise_fma((v[d]-mu)*r, splat2(w[d]), splat2(b[d]));
}

__global__ __launch_bounds__(TPB)
void decoder_fused(const float* __restrict__ x_batch,
                   const float* __restrict__ dec_ln_w, const float* __restrict__ dec_ln_b,
                   const float* __restrict__ qw, const float* __restrict__ qb,
                   const float* __restrict__ kw, const float* __restrict__ kb,
                   const float* __restrict__ vw, const float* __restrict__ vb,
                   const float* __restrict__ mha_ln_w, const float* __restrict__ mha_ln_b,
                   const unsigned* __restrict__ wsp,
                   const float* __restrict__ ffn_b2,
                   const float* __restrict__ ffn_ln_w, const float* __restrict__ ffn_ln_b,
                   float* __restrict__ out) {
    const int lane = threadIdx.x & 63;
    const int w    = blockIdx.x * (TPB/64) + (threadIdx.x >> 6);  // wave index in batch
    const int b    = blockIdx.y;
    const int p    = w * OUT_PER_WAVE - HALO + 2*lane;            // even seq position

    vf2 x2[DM];   // .x = pos p, .y = pos p+1
    if (p >= 0 && p + 1 < S_LEN) {
        const float4* s = reinterpret_cast<const float4*>(x_batch + ((size_t)b*S_LEN + p)*DM);
        float4 a0 = s[0], a1 = s[1], a2 = s[2];
        x2[0].x=a0.x; x2[1].x=a0.y; x2[2].x=a0.z; x2[3].x=a0.w; x2[4].x=a1.x; x2[5].x=a1.y;
        x2[0].y=a1.z; x2[1].y=a1.w; x2[2].y=a2.x; x2[3].y=a2.y; x2[4].y=a2.z; x2[5].y=a2.w;
    } else {
        // clamped pair collapses to a single row (p<0 -> row0 twice; tail -> row S-1 twice)
        const int pc = min(max(p, 0), S_LEN-1);
        const float2* s = reinterpret_cast<const float2*>(x_batch + ((size_t)b*S_LEN + pc)*DM);
        float2 a0 = s[0], a1 = s[1], a2 = s[2];
        x2[0] = splat2(a0.x); x2[1] = splat2(a0.y); x2[2] = splat2(a1.x);
        x2[3] = splat2(a1.y); x2[4] = splat2(a2.x); x2[5] = splat2(a2.y);
    }

    ln6v(x2, dec_ln_w, dec_ln_b);

#pragma unroll 1
    for (int li = 0; li < NLAYER; ++li) {
        // -------- two mha blocks: barrier-free neighbor exchange via shuffles --------
#pragma unroll 1
        for (int ai = 0; ai < 2; ++ai) {
            const int base = (li*2 + ai) * DM;
            vf2 xm[DM], xp[DM];
#pragma unroll
            for (int d = 0; d < DM; ++d) {
                float up = __shfl_up (x2[d].y, 1);   // pos p-1 (prev thread's odd)
                float dn = __shfl_down(x2[d].x, 1);  // pos p+2 (next thread's even)
                xm[d].x = (p <= 0) ? x2[d].x : up;   // k_in row0 = itself
                xm[d].y = x2[d].x;
                xp[d].x = x2[d].y;
                xp[d].y = (p + 1 >= S_LEN - 1) ? x2[d].y : dn;  // v_in last row = itself
            }
#pragma unroll
            for (int d = 0; d < DM; ++d) {
                vf2 q = __builtin_elementwise_fma(x2[d], splat2(qw[base+d]), splat2(qb[base+d]));
                vf2 k = __builtin_elementwise_fma(xm[d], splat2(kw[base+d]), splat2(kb[base+d]));
                vf2 v = __builtin_elementwise_fma(xp[d], splat2(vw[base+d]), splat2(vb[base+d]));
                vf2 teo = __builtin_elementwise_fma(q, q, -(k*v));
                x2[d] = __builtin_elementwise_fma(teo, splat2(1.0f/(float)S_LEN), x2[d]);
            }
            ln6v(x2, mha_ln_w + base, mha_ln_b + base);
        }

        // -------- FFN in packed f16, two positions per lane --------
        {
            const unsigned* w1p = wsp + (size_t)li*NFF*DM;
            const unsigned* b1p = wsp + B1P_OFF + (size_t)li*NFF;
            const unsigned* w2p = wsp + W2P_OFF + (size_t)li*NFF*DM;
            const float*    b2  = ffn_b2 + li*DM;

            vh2 xh[DM];
#pragma unroll
            for (int d = 0; d < DM; ++d)
                xh[d] = __builtin_bit_cast(vh2, __builtin_amdgcn_cvt_pkrtz(x2[d].x, x2[d].y));
            vh2 ya[DM], yb[DM];
#pragma unroll
            for (int d = 0; d < DM; ++d) { ya[d] = (vh2)(_Float16)0; yb[d] = (vh2)(_Float16)0; }

#pragma unroll 4
            for (int f = 0; f < NFF; f += 2) {
                vh2 h0 = bch2(b1p[f]);
                vh2 h1 = bch2(b1p[f+1]);
#pragma unroll
                for (int d = 0; d < DM; ++d) {
                    h0 = __builtin_elementwise_fma(xh[d], bch2(w1p[f*DM + d]),     h0);
                    h1 = __builtin_elementwise_fma(xh[d], bch2(w1p[(f+1)*DM + d]), h1);
                }
                vh2 z = (vh2)(_Float16)0;
                h0 = __builtin_elementwise_max(h0, z);
                h1 = __builtin_elementwise_max(h1, z);
#pragma unroll
                for (int d = 0; d < DM; ++d) {
                    ya[d] = __builtin_elementwise_fma(h0, bch2(w2p[f*DM + d]),     ya[d]);
                    yb[d] = __builtin_elementwise_fma(h1, bch2(w2p[(f+1)*DM + d]), yb[d]);
                }
            }
#pragma unroll
            for (int d = 0; d < DM; ++d) {
                x2[d].x = x2[d].x + b2[d] + ((float)ya[d].x + (float)yb[d].x);
                x2[d].y = x2[d].y + b2[d] + ((float)ya[d].y + (float)yb[d].y);
            }
            ln6v(x2, ffn_ln_w + li*DM, ffn_ln_b + li*DM);
        }
    }

    // lanes 4..59 hold the wave's 112 valid output positions
    if (lane >= HALO/2 && lane < 64 - HALO/2 + 4 - 8 + 60 - 56) {} // (no-op guard folded below)
    if (lane >= 4 && lane < 60 && p < S_LEN) {
        float4* dst = reinterpret_cast<float4*>(out + ((size_t)b*S_LEN + p)*DM);
        float4 a0, a1, a2;
        a0.x=x2[0].x; a0.y=x2[1].x; a0.z=x2[2].x; a0.w=x2[3].x;
        a1.x=x2[4].x; a1.y=x2[5].x; a1.z=x2[0].y; a1.w=x2[1].y;
        a2.x=x2[2].y; a2.y=x2[3].y; a2.z=x2[4].y; a2.w=x2[5].y;
        dst[0]=a0; dst[1]=a1; dst[2]=a2;
    }
}

extern "C" void kernel_launch(void* const* d_in, const int* in_sizes, int n_in,
                              void* d_out, int out_size, void* d_ws, size_t ws_size,
                              hipStream_t stream) {
    const float* x_batch  = (const float*)d_in[0];
    // d_in[1] enc_output: unused by the reference
    const float* dec_ln_w = (const float*)d_in[2];
    const float* dec_ln_b = (const float*)d_in[3];
    const float* qw       = (const float*)d_in[4];
    const float* qb       = (const float*)d_in[5];
    const float* kw       = (const float*)d_in[6];
    const float* kb       = (const float*)d_in[7];
    const float* vw       = (const float*)d_in[8];
    const float* vb       = (const float*)d_in[9];
    // d_in[10..11] ln1_w/ln1_b: dead (softmax of a seq-constant)
    const float* mha_ln_w = (const float*)d_in[12];
    const float* mha_ln_b = (const float*)d_in[13];
    const float* ffn_w1   = (const float*)d_in[14];
    const float* ffn_b1   = (const float*)d_in[15];
    const float* ffn_w2   = (const float*)d_in[16];
    const float* ffn_b2   = (const float*)d_in[17];
    const float* ffn_ln_w = (const float*)d_in[18];
    const float* ffn_ln_b = (const float*)d_in[19];
    float* out = (float*)d_out;
    unsigned* wsp = (unsigned*)d_ws;

    prep_weights<<<(PACK_TOTAL + 255)/256, 256, 0, stream>>>(ffn_w1, ffn_b1, ffn_w2, wsp);

    const int B = in_sizes[0] / (S_LEN * DM);   // 128
    dim3 grid(BLK_X, B);
    decoder_fused<<<grid, TPB, 0, stream>>>(
        x_batch, dec_ln_w, dec_ln_b, qw, qb, kw, kb, vw, vb,
        mha_ln_w, mha_ln_b, wsp, ffn_b2, ffn_ln_w, ffn_ln_b, out);
}

// Round 4
// 155.210 us; speedup vs baseline: 1.1246x; 1.0302x over previous
//
#include <hip/hip_runtime.h>

#define S_LEN  4096
#define DM     6
#define NLAYER 4
#define NFF    64
#define HALO   8
#define TPB    256
#define OUT_PER_WAVE 112              // wave holds 128 positions, outputs 112
#define BLK_X 10                      // ceil(ceil(4096/112)=37 waves / 4 per block)

typedef float    vf2 __attribute__((ext_vector_type(2)));
typedef _Float16 vh2 __attribute__((ext_vector_type(2)));

// Weight record per (layer, f-pair): 13 dwords, streamed linearly.
//  [0..5]  = {w1[2fp][d], w1[2fp+1][d]} for d=0..5   (f16 pair)
//  [6..11] = {w2[d][2fp], w2[d][2fp+1]} for d=0..5   (f16 pair)
//  [12]    = {b1[2fp], b1[2fp+1]}                    (f16 pair)
#define REC    13
#define FPAIRS (NFF/2)                     // 32
#define PACK_TOTAL (NLAYER*FPAIRS*REC)     // 1664 dwords = 6.7 KB

__device__ __forceinline__ vf2 splat2(float s){ vf2 r; r.x = s; r.y = s; return r; }
__device__ __forceinline__ vh2 bch2(unsigned u){ return __builtin_bit_cast(vh2, u); }

__device__ __forceinline__ unsigned pack2(float lo, float hi){
    _Float16 a = (_Float16)lo, b = (_Float16)hi;
    unsigned short ua = __builtin_bit_cast(unsigned short, a);
    unsigned short ub = __builtin_bit_cast(unsigned short, b);
    return (unsigned)ua | ((unsigned)ub << 16);
}

__global__ void prep_weights(const float* __restrict__ w1,
                             const float* __restrict__ b1,
                             const float* __restrict__ w2,
                             unsigned* __restrict__ ws) {
    int i = blockIdx.x * 256 + threadIdx.x;
    if (i >= PACK_TOTAL) return;
    int li = i / (FPAIRS*REC);
    int r  = i % (FPAIRS*REC);
    int fp = r / REC;
    int j  = r % REC;
    float lo, hi;
    if (j < 6) {                       // w1 [L][64][6]
        lo = w1[li*NFF*DM + (2*fp)*DM + j];
        hi = w1[li*NFF*DM + (2*fp+1)*DM + j];
    } else if (j < 12) {               // w2 [L][6][64]
        int d = j - 6;
        lo = w2[li*DM*NFF + d*NFF + 2*fp];
        hi = w2[li*DM*NFF + d*NFF + 2*fp + 1];
    } else {                           // b1 [L][64]
        lo = b1[li*NFF + 2*fp];
        hi = b1[li*NFF + 2*fp + 1];
    }
    ws[i] = pack2(lo, hi);
}

// LayerNorm over 6 dims, two seq positions packed per vf2.
__device__ __forceinline__ void ln6v(vf2* v, const float* __restrict__ w,
                                     const float* __restrict__ b) {
    vf2 mu = (((v[0]+v[1])+(v[2]+v[3]))+(v[4]+v[5])) * (1.0f/6.0f);
    vf2 var = splat2(0.0f);
#pragma unroll
    for (int d = 0; d < DM; ++d) { vf2 dd = v[d]-mu; var = __builtin_elementwise_fma(dd, dd, var); }
    vf2 a = var * (1.0f/6.0f) + splat2(1e-6f);
    vf2 r; r.x = rsqrtf(a.x); r.y = rsqrtf(a.y);
#pragma unroll
    for (int d = 0; d < DM; ++d)
        v[d] = __builtin_elementwise_fma((v[d]-mu)*r, splat2(w[d]), splat2(b[d]));
}

__global__ __launch_bounds__(TPB)
void decoder_fused(const float* __restrict__ x_batch,
                   const float* __restrict__ dec_ln_w, const float* __restrict__ dec_ln_b,
                   const float* __restrict__ qw, const float* __restrict__ qb,
                   const float* __restrict__ kw, const float* __restrict__ kb,
                   const float* __restrict__ vw, const float* __restrict__ vb,
                   const float* __restrict__ mha_ln_w, const float* __restrict__ mha_ln_b,
                   const unsigned* __restrict__ wsp,
                   const float* __restrict__ ffn_b2,
                   const float* __restrict__ ffn_ln_w, const float* __restrict__ ffn_ln_b,
                   float* __restrict__ out) {
    const int lane = threadIdx.x & 63;
    const int w    = blockIdx.x * (TPB/64) + (threadIdx.x >> 6);  // wave index in batch
    const int b    = blockIdx.y;
    const int p    = w * OUT_PER_WAVE - HALO + 2*lane;            // even seq position

    vf2 x2[DM];   // .x = pos p, .y = pos p+1
    if (p >= 0 && p + 1 < S_LEN) {
        const float4* s = reinterpret_cast<const float4*>(x_batch + ((size_t)b*S_LEN + p)*DM);
        float4 a0 = s[0], a1 = s[1], a2 = s[2];
        x2[0].x=a0.x; x2[1].x=a0.y; x2[2].x=a0.z; x2[3].x=a0.w; x2[4].x=a1.x; x2[5].x=a1.y;
        x2[0].y=a1.z; x2[1].y=a1.w; x2[2].y=a2.x; x2[3].y=a2.y; x2[4].y=a2.z; x2[5].y=a2.w;
    } else {
        const int pc = min(max(p, 0), S_LEN-1);
        const float2* s = reinterpret_cast<const float2*>(x_batch + ((size_t)b*S_LEN + pc)*DM);
        float2 a0 = s[0], a1 = s[1], a2 = s[2];
        x2[0] = splat2(a0.x); x2[1] = splat2(a0.y); x2[2] = splat2(a1.x);
        x2[3] = splat2(a1.y); x2[4] = splat2(a2.x); x2[5] = splat2(a2.y);
    }

    ln6v(x2, dec_ln_w, dec_ln_b);

#pragma unroll 1
    for (int li = 0; li < NLAYER; ++li) {
        // -------- two mha blocks: barrier-free neighbor exchange via shuffles --------
#pragma unroll 1
        for (int ai = 0; ai < 2; ++ai) {
            const int base = (li*2 + ai) * DM;
            vf2 xm[DM], xp[DM];
#pragma unroll
            for (int d = 0; d < DM; ++d) {
                float up = __shfl_up (x2[d].y, 1);   // pos p-1
                float dn = __shfl_down(x2[d].x, 1);  // pos p+2
                xm[d].x = (p <= 0) ? x2[d].x : up;
                xm[d].y = x2[d].x;
                xp[d].x = x2[d].y;
                xp[d].y = (p + 1 >= S_LEN - 1) ? x2[d].y : dn;
            }
#pragma unroll
            for (int d = 0; d < DM; ++d) {
                vf2 q = __builtin_elementwise_fma(x2[d], splat2(qw[base+d]), splat2(qb[base+d]));
                vf2 k = __builtin_elementwise_fma(xm[d], splat2(kw[base+d]), splat2(kb[base+d]));
                vf2 v = __builtin_elementwise_fma(xp[d], splat2(vw[base+d]), splat2(vb[base+d]));
                vf2 teo = __builtin_elementwise_fma(q, q, -(k*v));
                x2[d] = __builtin_elementwise_fma(teo, splat2(1.0f/(float)S_LEN), x2[d]);
            }
            ln6v(x2, mha_ln_w + base, mha_ln_b + base);
        }

        // -------- FFN: f-pairs in pk halves, position value duplicated --------
        {
            const unsigned* wl = wsp + (size_t)li * FPAIRS * REC;
            const float*    b2 = ffn_b2 + li*DM;

            vh2 xdA[DM], xdB[DM];        // {xA,xA}, {xB,xB} per dim
#pragma unroll
            for (int d = 0; d < DM; ++d) {
                _Float16 ha = (_Float16)x2[d].x, hb = (_Float16)x2[d].y;
                xdA[d].x = ha; xdA[d].y = ha;
                xdB[d].x = hb; xdB[d].y = hb;
            }
            vh2 accA[DM], accB[DM];      // halves = even-f / odd-f partial sums
#pragma unroll
            for (int d = 0; d < DM; ++d) { accA[d] = (vh2)(_Float16)0; accB[d] = (vh2)(_Float16)0; }

#pragma unroll 8
            for (int fp = 0; fp < FPAIRS; ++fp) {
                const unsigned* wp = wl + fp*REC;
                vh2 hA = bch2(wp[12]);             // {b1_f, b1_f1}
                vh2 hB = hA;
#pragma unroll
                for (int d = 0; d < DM; ++d) {
                    vh2 w1p = bch2(wp[d]);
                    hA = __builtin_elementwise_fma(xdA[d], w1p, hA);
                    hB = __builtin_elementwise_fma(xdB[d], w1p, hB);
                }
                vh2 z = (vh2)(_Float16)0;
                hA = __builtin_elementwise_max(hA, z);
                hB = __builtin_elementwise_max(hB, z);
#pragma unroll
                for (int d = 0; d < DM; ++d) {
                    vh2 w2p = bch2(wp[6+d]);
                    accA[d] = __builtin_elementwise_fma(hA, w2p, accA[d]);
                    accB[d] = __builtin_elementwise_fma(hB, w2p, accB[d]);
                }
            }
#pragma unroll
            for (int d = 0; d < DM; ++d) {
                x2[d].x = x2[d].x + b2[d] + ((float)accA[d].x + (float)accA[d].y);
                x2[d].y = x2[d].y + b2[d] + ((float)accB[d].x + (float)accB[d].y);
            }
            ln6v(x2, ffn_ln_w + li*DM, ffn_ln_b + li*DM);
        }
    }

    // lanes 4..59 hold the wave's 112 valid output positions
    if (lane >= 4 && lane < 60 && p < S_LEN) {
        float4* dst = reinterpret_cast<float4*>(out + ((size_t)b*S_LEN + p)*DM);
        float4 a0, a1, a2;
        a0.x=x2[0].x; a0.y=x2[1].x; a0.z=x2[2].x; a0.w=x2[3].x;
        a1.x=x2[4].x; a1.y=x2[5].x; a1.z=x2[0].y; a1.w=x2[1].y;
        a2.x=x2[2].y; a2.y=x2[3].y; a2.z=x2[4].y; a2.w=x2[5].y;
        dst[0]=a0; dst[1]=a1; dst[2]=a2;
    }
}

extern "C" void kernel_launch(void* const* d_in, const int* in_sizes, int n_in,
                              void* d_out, int out_size, void* d_ws, size_t ws_size,
                              hipStream_t stream) {
    const float* x_batch  = (const float*)d_in[0];
    // d_in[1] enc_output: unused by the reference
    const float* dec_ln_w = (const float*)d_in[2];
    const float* dec_ln_b = (const float*)d_in[3];
    const float* qw       = (const float*)d_in[4];
    const float* qb       = (const float*)d_in[5];
    const float* kw       = (const float*)d_in[6];
    const float* kb       = (const float*)d_in[7];
    const float* vw       = (const float*)d_in[8];
    const float* vb       = (const float*)d_in[9];
    // d_in[10..11] ln1_w/ln1_b: dead (softmax of a seq-constant)
    const float* mha_ln_w = (const float*)d_in[12];
    const float* mha_ln_b = (const float*)d_in[13];
    const float* ffn_w1   = (const float*)d_in[14];
    const float* ffn_b1   = (const float*)d_in[15];
    const float* ffn_w2   = (const float*)d_in[16];
    const float* ffn_b2   = (const float*)d_in[17];
    const float* ffn_ln_w = (const float*)d_in[18];
    const float* ffn_ln_b = (const float*)d_in[19];
    float* out = (float*)d_out;
    unsigned* wsp = (unsigned*)d_ws;

    prep_weights<<<(PACK_TOTAL + 255)/256, 256, 0, stream>>>(ffn_w1, ffn_b1, ffn_w2, wsp);

    const int B = in_sizes[0] / (S_LEN * DM);   // 128
    dim3 grid(BLK_X, B);
    decoder_fused<<<grid, TPB, 0, stream>>>(
        x_batch, dec_ln_w, dec_ln_b, qw, qb, kw, kb, vw, vb,
        mha_ln_w, mha_ln_b, wsp, ffn_b2, ffn_ln_w, ffn_ln_b, out);
}

// Round 5
// 140.785 us; speedup vs baseline: 1.2398x; 1.1025x over previous
//
#include <hip/hip_runtime.h>

#define S_LEN  4096
#define DM     6
#define NLAYER 4
#define NFF    64
#define HALO   8
#define TPB    256
#define OUT_PER_WAVE 112              // wave holds 128 positions, outputs 112
#define BLK_X 10                      // ceil(37 waves / 4 per block)

typedef float    vf2 __attribute__((ext_vector_type(2)));
typedef float    vf4 __attribute__((ext_vector_type(4)));
typedef _Float16 vh2 __attribute__((ext_vector_type(2)));
typedef _Float16 vh4 __attribute__((ext_vector_type(4)));

// d_ws frag layouts (dwords). Each entry: 2 f16 halves (j=2*dwj, 2*dwj+1).
// W1A[li][ftile][lane][dwj]: A-frag of W1 (m=f, k=d, d>=6 zero-padded)
// W2A[li][kstep][lane][dwj]: A-frag of W2 (m=d (rows>=6 zero), k=f)
#define W1A_OFF 0
#define W2A_OFF 2048
#define PACK_TOTAL 4096

// wave-private LDS: X (f16, 128 rows x 40B stride, k-pad pre-zeroed) + Yt (f32, 8 x 132dw)
#define XSTRIDE 40
#define XSZ (128*XSTRIDE)        // 5120 B
#define YSTRIDE 132              // dwords
#define YSZ (8*YSTRIDE*4)        // 4224 B
#define WAVE_LDS (XSZ + YSZ)     // 9344 B

__device__ __forceinline__ vf2 splat2(float s){ vf2 r; r.x = s; r.y = s; return r; }
__device__ __forceinline__ unsigned pkh(float a, float b){
    return __builtin_bit_cast(unsigned, __builtin_amdgcn_cvt_pkrtz(a, b));
}
__device__ __forceinline__ unsigned pack2(float lo, float hi){
    _Float16 a = (_Float16)lo, b = (_Float16)hi;
    unsigned short ua = __builtin_bit_cast(unsigned short, a);
    unsigned short ub = __builtin_bit_cast(unsigned short, b);
    return (unsigned)ua | ((unsigned)ub << 16);
}

__global__ void prep_frags(const float* __restrict__ w1,
                           const float* __restrict__ w2,
                           unsigned* __restrict__ ws) {
    int i = blockIdx.x * 256 + threadIdx.x;
    if (i >= PACK_TOTAL) return;
    int which = i >> 11;          // 0=W1A, 1=W2A
    int r  = i & 2047;
    int li = r >> 9;
    int q  = r & 511;
    int tile = q >> 7;            // ftile / kstep
    int rem  = q & 127;
    int lane = rem >> 1;
    int dwj  = rem & 1;
    int c = lane & 15, g = lane >> 4;
    float lo = 0.f, hi = 0.f;
    if (which == 0) {
        int f  = tile*16 + c;
        int d0 = g*4 + 2*dwj;
        if (d0   < DM) lo = w1[li*NFF*DM + f*DM + d0];
        if (d0+1 < DM) hi = w1[li*NFF*DM + f*DM + d0+1];
    } else {
        int d = c;
        int f = tile*16 + g*4 + 2*dwj;
        if (d < DM) { lo = w2[li*DM*NFF + d*NFF + f]; hi = w2[li*DM*NFF + d*NFF + f+1]; }
    }
    ws[i] = pack2(lo, hi);
}

// LayerNorm over 6 dims, two seq positions packed per vf2.
__device__ __forceinline__ void ln6v(vf2* v, const float* __restrict__ w,
                                     const float* __restrict__ b) {
    vf2 mu = (((v[0]+v[1])+(v[2]+v[3]))+(v[4]+v[5])) * (1.0f/6.0f);
    vf2 var = splat2(0.0f);
#pragma unroll
    for (int d = 0; d < DM; ++d) { vf2 dd = v[d]-mu; var = __builtin_elementwise_fma(dd, dd, var); }
    vf2 a = var * (1.0f/6.0f) + splat2(1e-6f);
    vf2 r; r.x = rsqrtf(a.x); r.y = rsqrtf(a.y);
#pragma unroll
    for (int d = 0; d < DM; ++d)
        v[d] = __builtin_elementwise_fma((v[d]-mu)*r, splat2(w[d]), splat2(b[d]));
}

__global__ __launch_bounds__(TPB)
void decoder_fused(const float* __restrict__ x_batch,
                   const float* __restrict__ dec_ln_w, const float* __restrict__ dec_ln_b,
                   const float* __restrict__ qw, const float* __restrict__ qb,
                   const float* __restrict__ kw, const float* __restrict__ kb,
                   const float* __restrict__ vw, const float* __restrict__ vb,
                   const float* __restrict__ mha_ln_w, const float* __restrict__ mha_ln_b,
                   const unsigned* __restrict__ wsp,
                   const float* __restrict__ ffn_b1, const float* __restrict__ ffn_b2,
                   const float* __restrict__ ffn_ln_w, const float* __restrict__ ffn_ln_b,
                   float* __restrict__ out) {
    const int lane = threadIdx.x & 63;
    const int wid  = threadIdx.x >> 6;
    const int w    = blockIdx.x * (TPB/64) + wid;                 // wave index in batch
    const int b    = blockIdx.y;
    const int p    = w * OUT_PER_WAVE - HALO + 2*lane;            // even seq position
    const int c    = lane & 15, g = lane >> 4;

    __shared__ __align__(16) char smem[(TPB/64) * WAVE_LDS];
    char* wbase = smem + wid * WAVE_LDS;
    char* Xb = wbase;
    char* Yb = wbase + XSZ;

    // zero X region once (pads bytes 12..39 of each row must be 0 for k>=6)
    {
        uint4 z = make_uint4(0,0,0,0);
#pragma unroll
        for (int i = 0; i < 5; ++i) *(uint4*)(wbase + lane*80 + i*16) = z;
    }

    vf2 x2[DM];   // .x = pos p, .y = pos p+1
    if (p >= 0 && p + 1 < S_LEN) {
        const float4* s = reinterpret_cast<const float4*>(x_batch + ((size_t)b*S_LEN + p)*DM);
        float4 a0 = s[0], a1 = s[1], a2 = s[2];
        x2[0].x=a0.x; x2[1].x=a0.y; x2[2].x=a0.z; x2[3].x=a0.w; x2[4].x=a1.x; x2[5].x=a1.y;
        x2[0].y=a1.z; x2[1].y=a1.w; x2[2].y=a2.x; x2[3].y=a2.y; x2[4].y=a2.z; x2[5].y=a2.w;
    } else {
        const int pc = min(max(p, 0), S_LEN-1);
        const float2* s = reinterpret_cast<const float2*>(x_batch + ((size_t)b*S_LEN + pc)*DM);
        float2 a0 = s[0], a1 = s[1], a2 = s[2];
        x2[0] = splat2(a0.x); x2[1] = splat2(a0.y); x2[2] = splat2(a1.x);
        x2[3] = splat2(a1.y); x2[4] = splat2(a2.x); x2[5] = splat2(a2.y);
    }

    ln6v(x2, dec_ln_w, dec_ln_b);

#pragma unroll 1
    for (int li = 0; li < NLAYER; ++li) {
        // prefetch this layer's FFN frags early (consumed after ~1200 inst of mha)
        vh4 w1f[4], w2f[4]; vf4 b1f[4];
#pragma unroll
        for (int mt = 0; mt < 4; ++mt) {
            uint2 u = *((const uint2*)wsp + (li*4 + mt)*64 + lane);
            w1f[mt] = __builtin_bit_cast(vh4, u);
            uint2 v = *((const uint2*)wsp + (W2A_OFF/2) + (li*4 + mt)*64 + lane);
            w2f[mt] = __builtin_bit_cast(vh4, v);
            float4 bb = *reinterpret_cast<const float4*>(ffn_b1 + li*NFF + mt*16 + g*4);
            vf4 bv; bv.x=bb.x; bv.y=bb.y; bv.z=bb.z; bv.w=bb.w;
            b1f[mt] = bv;
        }

        // -------- two mha blocks: barrier-free neighbor exchange via shuffles --------
#pragma unroll 1
        for (int ai = 0; ai < 2; ++ai) {
            const int base = (li*2 + ai) * DM;
            vf2 xm[DM], xp[DM];
#pragma unroll
            for (int d = 0; d < DM; ++d) {
                float up = __shfl_up (x2[d].y, 1);   // pos p-1
                float dn = __shfl_down(x2[d].x, 1);  // pos p+2
                xm[d].x = (p <= 0) ? x2[d].x : up;
                xm[d].y = x2[d].x;
                xp[d].x = x2[d].y;
                xp[d].y = (p + 1 >= S_LEN - 1) ? x2[d].y : dn;
            }
#pragma unroll
            for (int d = 0; d < DM; ++d) {
                vf2 q = __builtin_elementwise_fma(x2[d], splat2(qw[base+d]), splat2(qb[base+d]));
                vf2 k = __builtin_elementwise_fma(xm[d], splat2(kw[base+d]), splat2(kb[base+d]));
                vf2 v = __builtin_elementwise_fma(xp[d], splat2(vw[base+d]), splat2(vb[base+d]));
                vf2 teo = __builtin_elementwise_fma(q, q, -(k*v));
                x2[d] = __builtin_elementwise_fma(teo, splat2(1.0f/(float)S_LEN), x2[d]);
            }
            ln6v(x2, mha_ln_w + base, mha_ln_b + base);
        }

        // -------- FFN via per-wave MFMA: Ht = W1·Xt, Yt = W2·relu(Ht+b1) --------
        {
            // stage X as f16 rows (pos-major), pads already zero
            {
                unsigned d0 = pkh(x2[0].x,x2[1].x), d1 = pkh(x2[2].x,x2[3].x), d2 = pkh(x2[4].x,x2[5].x);
                unsigned e0 = pkh(x2[0].y,x2[1].y), e1 = pkh(x2[2].y,x2[3].y), e2 = pkh(x2[4].y,x2[5].y);
                char* r0 = Xb + (2*lane)*XSTRIDE;
                *(uint2*)r0 = make_uint2(d0,d1); *(unsigned*)(r0+8) = d2;
                char* r1 = r0 + XSTRIDE;
                *(uint2*)r1 = make_uint2(e0,e1); *(unsigned*)(r1+8) = e2;
            }
            vh4 bfrag[8];
#pragma unroll
            for (int t = 0; t < 8; ++t)
                bfrag[t] = *(const vh4*)(Xb + (16*t + c)*XSTRIDE + g*8);

#pragma unroll
            for (int t = 0; t < 8; ++t) {
                vh4 hb[4];
#pragma unroll
                for (int ft = 0; ft < 4; ++ft) {
                    vf4 hc = __builtin_amdgcn_mfma_f32_16x16x16f16(w1f[ft], bfrag[t], b1f[ft], 0, 0, 0);
                    unsigned lo = pkh(fmaxf(hc.x,0.f), fmaxf(hc.y,0.f));
                    unsigned hi = pkh(fmaxf(hc.z,0.f), fmaxf(hc.w,0.f));
                    uint2 u = make_uint2(lo, hi);
                    hb[ft] = __builtin_bit_cast(vh4, u);   // C/D layout == B layout for 16x16x16
                }
                vf4 yacc; yacc.x=0.f; yacc.y=0.f; yacc.z=0.f; yacc.w=0.f;
#pragma unroll
                for (int ks = 0; ks < 4; ++ks)
                    yacc = __builtin_amdgcn_mfma_f32_16x16x16f16(w2f[ks], hb[ks], yacc, 0, 0, 0);
                if (lane < 32) {                           // rows 0-7 only (d<6 + 2 zero rows)
                    int col = 16*t + c;
                    float* yp = (float*)Yb;
                    yp[(g*4+0)*YSTRIDE + col] = yacc.x;
                    yp[(g*4+1)*YSTRIDE + col] = yacc.y;
                    yp[(g*4+2)*YSTRIDE + col] = yacc.z;
                    yp[(g*4+3)*YSTRIDE + col] = yacc.w;
                }
            }
            const float* b2 = ffn_b2 + li*DM;
#pragma unroll
            for (int d = 0; d < DM; ++d) {
                float2 yv = *(const float2*)((float*)Yb + d*YSTRIDE + 2*lane);
                vf2 t2; t2.x = yv.x; t2.y = yv.y;
                x2[d] = x2[d] + splat2(b2[d]) + t2;
            }
            ln6v(x2, ffn_ln_w + li*DM, ffn_ln_b + li*DM);
        }
    }

    // lanes 4..59 hold the wave's 112 valid output positions
    if (lane >= 4 && lane < 60 && p < S_LEN) {
        float4* dst = reinterpret_cast<float4*>(out + ((size_t)b*S_LEN + p)*DM);
        float4 a0, a1, a2;
        a0.x=x2[0].x; a0.y=x2[1].x; a0.z=x2[2].x; a0.w=x2[3].x;
        a1.x=x2[4].x; a1.y=x2[5].x; a1.z=x2[0].y; a1.w=x2[1].y;
        a2.x=x2[2].y; a2.y=x2[3].y; a2.z=x2[4].y; a2.w=x2[5].y;
        dst[0]=a0; dst[1]=a1; dst[2]=a2;
    }
}

extern "C" void kernel_launch(void* const* d_in, const int* in_sizes, int n_in,
                              void* d_out, int out_size, void* d_ws, size_t ws_size,
                              hipStream_t stream) {
    const float* x_batch  = (const float*)d_in[0];
    // d_in[1] enc_output: unused by the reference
    const float* dec_ln_w = (const float*)d_in[2];
    const float* dec_ln_b = (const float*)d_in[3];
    const float* qw       = (const float*)d_in[4];
    const float* qb       = (const float*)d_in[5];
    const float* kw       = (const float*)d_in[6];
    const float* kb       = (const float*)d_in[7];
    const float* vw       = (const float*)d_in[8];
    const float* vb       = (const float*)d_in[9];
    // d_in[10..11] ln1_w/ln1_b: dead (softmax of a seq-constant)
    const float* mha_ln_w = (const float*)d_in[12];
    const float* mha_ln_b = (const float*)d_in[13];
    const float* ffn_w1   = (const float*)d_in[14];
    const float* ffn_b1   = (const float*)d_in[15];
    const float* ffn_w2   = (const float*)d_in[16];
    const float* ffn_b2   = (const float*)d_in[17];
    const float* ffn_ln_w = (const float*)d_in[18];
    const float* ffn_ln_b = (const float*)d_in[19];
    float* out = (float*)d_out;
    unsigned* wsp = (unsigned*)d_ws;

    prep_frags<<<(PACK_TOTAL + 255)/256, 256, 0, stream>>>(ffn_w1, ffn_w2, wsp);

    const int B = in_sizes[0] / (S_LEN * DM);   // 128
    dim3 grid(BLK_X, B);
    decoder_fused<<<grid, TPB, 0, stream>>>(
        x_batch, dec_ln_w, dec_ln_b, qw, qb, kw, kb, vw, vb,
        mha_ln_w, mha_ln_b, wsp, ffn_b1, ffn_b2, ffn_ln_w, ffn_ln_b, out);
}

// Round 7
// 140.499 us; speedup vs baseline: 1.2424x; 1.0020x over previous
//
#include <hip/hip_runtime.h>

#define S_LEN  4096
#define DM     6
#define NLAYER 4
#define NFF    64
#define HALO   8
#define TPB    256
#define OUT_PER_WAVE 112              // wave holds 128 positions, outputs 112
#define BLK_X 10                      // ceil(37 waves / 4 per block)

typedef float    vf2 __attribute__((ext_vector_type(2)));
typedef float    vf4 __attribute__((ext_vector_type(4)));
typedef _Float16 vh2 __attribute__((ext_vector_type(2)));
typedef _Float16 vh4 __attribute__((ext_vector_type(4)));

// d_ws frag layouts (dwords). Each entry: 2 f16 halves (j=2*dwj, 2*dwj+1).
// W1A[li][ftile][lane][dwj]: A-frag of W1 (m=f, k=d, d>=6 zero-padded)
// W2A[li][kstep][lane][dwj]: A-frag of W2 (m=d (rows>=6 zero), k=f)
#define W1A_OFF 0
#define W2A_OFF 2048
#define PACK_TOTAL 4096

// wave-private LDS:
//  X: 128 tight 16-B rows [pk01,pk23,pk45,0]; k=6,7 pad stored, k=8..15
//     handled by zeroing g>=2 fragments at the destination (no pad storage).
//  Yt: f32 [6][130] readback (rows 6,7 of the MFMA output never read -> dropped)
#define XSZ (128*16)             // 2048 B
#define YSTRIDE 130              // dwords
#define YROWS 6
#define YSZ (YROWS*YSTRIDE*4)    // 3120 B
#define WAVE_LDS (XSZ + YSZ)     // 5168 B -> 20672 B/block -> 7 blocks/CU by LDS

__device__ __forceinline__ vf2 splat2(float s){ vf2 r; r.x = s; r.y = s; return r; }
__device__ __forceinline__ unsigned pkh(float a, float b){
    return __builtin_bit_cast(unsigned, __builtin_amdgcn_cvt_pkrtz(a, b));
}
__device__ __forceinline__ unsigned pack2(float lo, float hi){
    _Float16 a = (_Float16)lo, b = (_Float16)hi;
    unsigned short ua = __builtin_bit_cast(unsigned short, a);
    unsigned short ub = __builtin_bit_cast(unsigned short, b);
    return (unsigned)ua | ((unsigned)ub << 16);
}

__global__ void prep_frags(const float* __restrict__ w1,
                           const float* __restrict__ w2,
                           unsigned* __restrict__ ws) {
    int i = blockIdx.x * 256 + threadIdx.x;
    if (i >= PACK_TOTAL) return;
    int which = i >> 11;          // 0=W1A, 1=W2A
    int r  = i & 2047;
    int li = r >> 9;
    int q  = r & 511;
    int tile = q >> 7;            // ftile / kstep
    int rem  = q & 127;
    int lane = rem >> 1;
    int dwj  = rem & 1;
    int c = lane & 15, g = lane >> 4;
    float lo = 0.f, hi = 0.f;
    if (which == 0) {
        int f  = tile*16 + c;
        int d0 = g*4 + 2*dwj;
        if (d0   < DM) lo = w1[li*NFF*DM + f*DM + d0];
        if (d0+1 < DM) hi = w1[li*NFF*DM + f*DM + d0+1];
    } else {
        int d = c;
        int f = tile*16 + g*4 + 2*dwj;
        if (d < DM) { lo = w2[li*DM*NFF + d*NFF + f]; hi = w2[li*DM*NFF + d*NFF + f+1]; }
    }
    ws[i] = pack2(lo, hi);
}

// LayerNorm over 6 dims, two seq positions packed per vf2.
__device__ __forceinline__ void ln6v(vf2* v, const float* __restrict__ w,
                                     const float* __restrict__ b) {
    vf2 mu = (((v[0]+v[1])+(v[2]+v[3]))+(v[4]+v[5])) * (1.0f/6.0f);
    vf2 var = splat2(0.0f);
#pragma unroll
    for (int d = 0; d < DM; ++d) { vf2 dd = v[d]-mu; var = __builtin_elementwise_fma(dd, dd, var); }
    vf2 a = var * (1.0f/6.0f) + splat2(1e-6f);
    vf2 r; r.x = rsqrtf(a.x); r.y = rsqrtf(a.y);
#pragma unroll
    for (int d = 0; d < DM; ++d)
        v[d] = __builtin_elementwise_fma((v[d]-mu)*r, splat2(w[d]), splat2(b[d]));
}

__global__ __launch_bounds__(TPB)
void decoder_fused(const float* __restrict__ x_batch,
                   const float* __restrict__ dec_ln_w, const float* __restrict__ dec_ln_b,
                   const float* __restrict__ qw, const float* __restrict__ qb,
                   const float* __restrict__ kw, const float* __restrict__ kb,
                   const float* __restrict__ vw, const float* __restrict__ vb,
                   const float* __restrict__ mha_ln_w, const float* __restrict__ mha_ln_b,
                   const unsigned* __restrict__ wsp,
                   const float* __restrict__ ffn_b1, const float* __restrict__ ffn_b2,
                   const float* __restrict__ ffn_ln_w, const float* __restrict__ ffn_ln_b,
                   float* __restrict__ out) {
    const int lane = threadIdx.x & 63;
    const int wid  = threadIdx.x >> 6;
    const int w    = blockIdx.x * (TPB/64) + wid;                 // wave index in batch
    const int b    = blockIdx.y;
    const int p    = w * OUT_PER_WAVE - HALO + 2*lane;            // even seq position
    const int c    = lane & 15, g = lane >> 4;

    __shared__ __align__(16) char smem[(TPB/64) * WAVE_LDS];
    char* wbase = smem + wid * WAVE_LDS;
    char* Xb = wbase;
    char* Yb = wbase + XSZ;

    vf2 x2[DM];   // .x = pos p, .y = pos p+1
    if (p >= 0 && p + 1 < S_LEN) {
        const float4* s = reinterpret_cast<const float4*>(x_batch + ((size_t)b*S_LEN + p)*DM);
        float4 a0 = s[0], a1 = s[1], a2 = s[2];
        x2[0].x=a0.x; x2[1].x=a0.y; x2[2].x=a0.z; x2[3].x=a0.w; x2[4].x=a1.x; x2[5].x=a1.y;
        x2[0].y=a1.z; x2[1].y=a1.w; x2[2].y=a2.x; x2[3].y=a2.y; x2[4].y=a2.z; x2[5].y=a2.w;
    } else {
        const int pc = min(max(p, 0), S_LEN-1);
        const float2* s = reinterpret_cast<const float2*>(x_batch + ((size_t)b*S_LEN + pc)*DM);
        float2 a0 = s[0], a1 = s[1], a2 = s[2];
        x2[0] = splat2(a0.x); x2[1] = splat2(a0.y); x2[2] = splat2(a1.x);
        x2[3] = splat2(a1.y); x2[4] = splat2(a2.x); x2[5] = splat2(a2.y);
    }

    ln6v(x2, dec_ln_w, dec_ln_b);

#pragma unroll 1
    for (int li = 0; li < NLAYER; ++li) {
        // prefetch this layer's FFN frags early (consumed after the mha blocks)
        vh4 w1f[4], w2f[4]; vf4 b1f[4];
#pragma unroll
        for (int mt = 0; mt < 4; ++mt) {
            uint2 u = *((const uint2*)wsp + (li*4 + mt)*64 + lane);
            w1f[mt] = __builtin_bit_cast(vh4, u);
            uint2 v = *((const uint2*)wsp + (W2A_OFF/2) + (li*4 + mt)*64 + lane);
            w2f[mt] = __builtin_bit_cast(vh4, v);
            float4 bb = *reinterpret_cast<const float4*>(ffn_b1 + li*NFF + mt*16 + g*4);
            vf4 bv; bv.x=bb.x; bv.y=bb.y; bv.z=bb.z; bv.w=bb.w;
            b1f[mt] = bv;
        }

        // -------- two mha blocks: barrier-free neighbor exchange via shuffles --------
#pragma unroll 1
        for (int ai = 0; ai < 2; ++ai) {
            const int base = (li*2 + ai) * DM;
            vf2 xm[DM], xp[DM];
#pragma unroll
            for (int d = 0; d < DM; ++d) {
                float up = __shfl_up (x2[d].y, 1);   // pos p-1
                float dn = __shfl_down(x2[d].x, 1);  // pos p+2
                xm[d].x = (p <= 0) ? x2[d].x : up;
                xm[d].y = x2[d].x;
                xp[d].x = x2[d].y;
                xp[d].y = (p + 1 >= S_LEN - 1) ? x2[d].y : dn;
            }
#pragma unroll
            for (int d = 0; d < DM; ++d) {
                vf2 q = __builtin_elementwise_fma(x2[d], splat2(qw[base+d]), splat2(qb[base+d]));
                vf2 k = __builtin_elementwise_fma(xm[d], splat2(kw[base+d]), splat2(kb[base+d]));
                vf2 v = __builtin_elementwise_fma(xp[d], splat2(vw[base+d]), splat2(vb[base+d]));
                vf2 teo = __builtin_elementwise_fma(q, q, -(k*v));
                x2[d] = __builtin_elementwise_fma(teo, splat2(1.0f/(float)S_LEN), x2[d]);
            }
            ln6v(x2, mha_ln_w + base, mha_ln_b + base);
        }

        // -------- FFN via per-wave MFMA: Ht = W1·Xt, Yt = W2·relu(Ht+b1) --------
        {
            // stage X: lane's two positions as tight 16B rows (k=6,7 pad in-store)
            {
                char* r0 = Xb + lane*32;
                *(uint4*)r0      = make_uint4(pkh(x2[0].x,x2[1].x), pkh(x2[2].x,x2[3].x),
                                              pkh(x2[4].x,x2[5].x), 0u);
                *(uint4*)(r0+16) = make_uint4(pkh(x2[0].y,x2[1].y), pkh(x2[2].y,x2[3].y),
                                              pkh(x2[4].y,x2[5].y), 0u);
            }
            // B-frags: k = g*4..g*4+3. g=0 -> dwords 0,1; g=1 -> dwords 2,3
            // (incl. stored zero pad); g>=2 -> k in 8..15 must be ZERO: mask at dest.
            vh4 bfrag[8];
#pragma unroll
            for (int t = 0; t < 8; ++t) {
                vh4 v = *(const vh4*)(Xb + (16*t + c)*16 + (g&1)*8);
                if (g >= 2) v = (vh4)(_Float16)0;
                bfrag[t] = v;
            }

#pragma unroll
            for (int t = 0; t < 8; ++t) {
                vh4 hb[4];
#pragma unroll
                for (int ft = 0; ft < 4; ++ft) {
                    vf4 hc = __builtin_amdgcn_mfma_f32_16x16x16f16(w1f[ft], bfrag[t], b1f[ft], 0, 0, 0);
                    uint2 u = make_uint2(pkh(hc.x,hc.y), pkh(hc.z,hc.w));
                    vh4 hraw = __builtin_bit_cast(vh4, u);
                    vh4 z4 = (vh4)(_Float16)0;
                    hb[ft] = __builtin_elementwise_max(hraw, z4);   // relu in pk-f16
                }
                vf4 yacc; yacc.x=0.f; yacc.y=0.f; yacc.z=0.f; yacc.w=0.f;
#pragma unroll
                for (int ks = 0; ks < 4; ++ks)
                    yacc = __builtin_amdgcn_mfma_f32_16x16x16f16(w2f[ks], hb[ks], yacc, 0, 0, 0);
                int col = 16*t + c;
                float* yp = (float*)Yb;
                if (lane < 32) {                 // rows g*4, g*4+1  (g=1 -> rows 4,5)
                    yp[(g*4+0)*YSTRIDE + col] = yacc.x;
                    yp[(g*4+1)*YSTRIDE + col] = yacc.y;
                }
                if (lane < 16) {                 // rows 2,3 (g=0 only; rows 6,7 dropped)
                    yp[2*YSTRIDE + col] = yacc.z;
                    yp[3*YSTRIDE + col] = yacc.w;
                }
            }
            const float* b2 = ffn_b2 + li*DM;
#pragma unroll
            for (int d = 0; d < DM; ++d) {
                float2 yv = *(const float2*)((float*)Yb + d*YSTRIDE + 2*lane);
                vf2 t2; t2.x = yv.x; t2.y = yv.y;
                x2[d] = x2[d] + splat2(b2[d]) + t2;
            }
            ln6v(x2, ffn_ln_w + li*DM, ffn_ln_b + li*DM);
        }
    }

    // lanes 4..59 hold the wave's 112 valid output positions
    if (lane >= 4 && lane < 60 && p < S_LEN) {
        float4* dst = reinterpret_cast<float4*>(out + ((size_t)b*S_LEN + p)*DM);
        float4 a0, a1, a2;
        a0.x=x2[0].x; a0.y=x2[1].x; a0.z=x2[2].x; a0.w=x2[3].x;
        a1.x=x2[4].x; a1.y=x2[5].x; a1.z=x2[0].y; a1.w=x2[1].y;
        a2.x=x2[2].y; a2.y=x2[3].y; a2.z=x2[4].y; a2.w=x2[5].y;
        dst[0]=a0; dst[1]=a1; dst[2]=a2;
    }
}

extern "C" void kernel_launch(void* const* d_in, const int* in_sizes, int n_in,
                              void* d_out, int out_size, void* d_ws, size_t ws_size,
                              hipStream_t stream) {
    const float* x_batch  = (const float*)d_in[0];
    // d_in[1] enc_output: unused by the reference
    const float* dec_ln_w = (const float*)d_in[2];
    const float* dec_ln_b = (const float*)d_in[3];
    const float* qw       = (const float*)d_in[4];
    const float* qb       = (const float*)d_in[5];
    const float* kw       = (const float*)d_in[6];
    const float* kb       = (const float*)d_in[7];
    const float* vw       = (const float*)d_in[8];
    const float* vb       = (const float*)d_in[9];
    // d_in[10..11] ln1_w/ln1_b: dead (softmax of a seq-constant)
    const float* mha_ln_w = (const float*)d_in[12];
    const float* mha_ln_b = (const float*)d_in[13];
    const float* ffn_w1   = (const float*)d_in[14];
    const float* ffn_b1   = (const float*)d_in[15];
    const float* ffn_w2   = (const float*)d_in[16];
    const float* ffn_b2   = (const float*)d_in[17];
    const float* ffn_ln_w = (const float*)d_in[18];
    const float* ffn_ln_b = (const float*)d_in[19];
    float* out = (float*)d_out;
    unsigned* wsp = (unsigned*)d_ws;

    prep_frags<<<(PACK_TOTAL + 255)/256, 256, 0, stream>>>(ffn_w1, ffn_w2, wsp);

    const int B = in_sizes[0] / (S_LEN * DM);   // 128
    dim3 grid(BLK_X, B);
    decoder_fused<<<grid, TPB, 0, stream>>>(
        x_batch, dec_ln_w, dec_ln_b, qw, qb, kw, kb, vw, vb,
        mha_ln_w, mha_ln_b, wsp, ffn_b1, ffn_b2, ffn_ln_w, ffn_ln_b, out);
}